// Round 1
// baseline (121.378 us; speedup 1.0000x reference)
//
#include <hip/hip_runtime.h>
#include <math.h>

// Problem constants (fixed by setup_inputs)
constexpr int B    = 64;
constexpr int D    = 1536;
constexpr int H    = 384;          // image H=W
constexpr int WS   = 16;           // window grid
constexpr int NW   = WS * WS;      // 256 windows per image
constexpr int SUB  = H / WS;       // 24 pixels per window side
constexpr int WELEM = SUB * SUB;   // 576 pixels per window
constexpr int IMG  = H * H;        // 147456
constexpr int TOT  = B * IMG;      // 9437184 entropy elements
constexpr int TOTW = B * NW;       // 16384 total windows

// ---------------------------------------------------------------------------
// Kernel A: entropy = -p*log(max(p,1e-5)), p = sigmoid(x). Double internally
// for a best-estimate "true" value, stored as f32.
__global__ void entropy_kernel(const float* __restrict__ preds,
                               float* __restrict__ ent) {
    int i = blockIdx.x * blockDim.x + threadIdx.x;
    if (i >= TOT) return;
    double x = (double)preds[i];
    double p = 1.0 / (1.0 + exp(-x));
    double pc = p < 1e-5 ? 1e-5 : p;
    ent[i] = (float)(-p * log(pc));
}

// ---------------------------------------------------------------------------
// Kernel B: one wave (64 lanes) per window. Pool 24x24 entropy block in
// double, round mean to f32, compare against f32 threshold (matching JAX's
// weak-typed f32 compare). Writes mask (as 0.0/1.0 f32) and an int flag.
__global__ void pool_kernel(const float* __restrict__ ent,
                            float* __restrict__ maskOut,
                            int* __restrict__ flags) {
    int w  = blockIdx.x;           // global window id, row-major (b, wy, wx)
    int b  = w / NW;
    int wi = w % NW;
    int wy = wi / WS, wx = wi % WS;
    const float* basep = ent + (size_t)b * IMG + (size_t)(wy * SUB) * H + wx * SUB;

    double s = 0.0;
    for (int e = threadIdx.x; e < WELEM; e += 64) {
        int r = e / SUB, c = e % SUB;
        s += (double)basep[r * H + c];
    }
    // wave-64 reduction
    for (int off = 32; off > 0; off >>= 1)
        s += __shfl_down(s, off, 64);

    if (threadIdx.x == 0) {
        float score = (float)(s / (double)WELEM);
        int sel = (score > 0.299f) ? 1 : 0;
        maskOut[w] = sel ? 1.0f : 0.0f;
        flags[w]   = sel;
    }
}

// ---------------------------------------------------------------------------
// Kernel C: exclusive prefix sum over 16384 flags (single block, 1024 thr,
// 16 chunks of 1024 with Hillis-Steele block scan).
__global__ void scan_kernel(const int* __restrict__ flags,
                            int* __restrict__ pos) {
    __shared__ int sh[1024];
    __shared__ int carry;
    if (threadIdx.x == 0) carry = 0;
    __syncthreads();

    for (int base = 0; base < TOTW; base += 1024) {
        int v = flags[base + threadIdx.x];
        sh[threadIdx.x] = v;
        __syncthreads();
        for (int off = 1; off < 1024; off <<= 1) {
            int t = (threadIdx.x >= off) ? sh[threadIdx.x - off] : 0;
            __syncthreads();
            sh[threadIdx.x] += t;
            __syncthreads();
        }
        int excl = carry + sh[threadIdx.x] - v;   // exclusive prefix
        pos[base + threadIdx.x] = excl;
        __syncthreads();                          // everyone read carry/sh
        if (threadIdx.x == 1023) carry += sh[1023];
        __syncthreads();
    }
}

// ---------------------------------------------------------------------------
// Kernel D: one block per window; selected windows copy their h_inputs row
// and the image's input_features row to compacted slots, plus (y,x) coords.
__global__ void gather_kernel(const float* __restrict__ inF,
                              const float* __restrict__ hIn,
                              const int* __restrict__ flags,
                              const int* __restrict__ pos,
                              float* __restrict__ outL,
                              float* __restrict__ outH,
                              float* __restrict__ coords) {
    int w = blockIdx.x;
    if (!flags[w]) return;
    int k  = pos[w];
    int b  = w / NW;
    int wi = w % NW;

    const float4* src_h = (const float4*)(hIn + (size_t)w * D);
    const float4* src_l = (const float4*)(inF + (size_t)b * D);
    float4* dst_h = (float4*)(outH + (size_t)k * D);
    float4* dst_l = (float4*)(outL + (size_t)k * D);

    for (int i = threadIdx.x; i < D / 4; i += blockDim.x) {
        dst_h[i] = src_h[i];
        dst_l[i] = src_l[i];
    }
    if (threadIdx.x == 0) {
        coords[2 * (size_t)k]     = (float)(wi / WS);
        coords[2 * (size_t)k + 1] = (float)(wi % WS);
    }
}

// ---------------------------------------------------------------------------
extern "C" void kernel_launch(void* const* d_in, const int* in_sizes, int n_in,
                              void* d_out, int out_size, void* d_ws, size_t ws_size,
                              hipStream_t stream) {
    const float* input_features = (const float*)d_in[0];   // [B, D]
    const float* h_inputs       = (const float*)d_in[1];   // [B, NW, D]
    const float* preds          = (const float*)d_in[2];   // [B, 1, H, H]
    float* out = (float*)d_out;

    // out layout: l[K,D] | h[K,D] | mask[TOTW] | coords[K,2] | entropy[TOT]
    int K = (out_size - TOT - TOTW) / (2 * D + 2);
    float* outL      = out;
    float* outH      = out + (size_t)K * D;
    float* outMask   = out + (size_t)2 * K * D;
    float* outCoords = outMask + TOTW;
    float* outEnt    = outCoords + (size_t)2 * K;

    int* flags = (int*)d_ws;          // [TOTW]
    int* pos   = flags + TOTW;        // [TOTW]

    entropy_kernel<<<(TOT + 255) / 256, 256, 0, stream>>>(preds, outEnt);
    pool_kernel<<<TOTW, 64, 0, stream>>>(outEnt, outMask, flags);
    scan_kernel<<<1, 1024, 0, stream>>>(flags, pos);
    gather_kernel<<<TOTW, 256, 0, stream>>>(input_features, h_inputs, flags, pos,
                                            outL, outH, outCoords);
}

// Round 3
// 87.366 us; speedup vs baseline: 1.3893x; 1.3893x over previous
//
#include <hip/hip_runtime.h>
#include <math.h>

// Problem constants (fixed by setup_inputs)
constexpr int B     = 64;
constexpr int D     = 1536;
constexpr int H     = 384;          // image H=W
constexpr int WS    = 16;           // window grid
constexpr int NW    = WS * WS;      // 256 windows per image
constexpr int SUB   = H / WS;       // 24 pixels per window side
constexpr int WELEM = SUB * SUB;    // 576 pixels per window
constexpr int IMG   = H * H;        // 147456
constexpr int TOT   = B * IMG;      // 9437184 entropy elements
constexpr int TOTW  = B * NW;       // 16384 total windows
constexpr int LISTCAP = TOTW - 1;   // list shares pos region (16384 ints - count)

// ---------------------------------------------------------------------------
// Kernel A (fused entropy + pool): block = (b, wy) band of 24 rows x 384 cols.
// 384 threads, one column each -> perfectly coalesced row reads/writes.
// f32 fast-path entropy; f64 accumulation of the window sum (cheap adds).
// Windows within 1e-4 of the threshold go to a precise-recompute list
// (fast-vs-precise score error is ~3e-7, 300x inside the margin).
__global__ void fused_kernel(const float* __restrict__ preds,
                             float* __restrict__ ent,
                             float* __restrict__ maskOut,
                             int* __restrict__ flags,
                             int* __restrict__ count,
                             int* __restrict__ list) {
    __shared__ double colsum[H];
    int b  = blockIdx.x >> 4;       // grid = B*16, blockIdx = b*16 + wy
    int wy = blockIdx.x & 15;
    int c  = threadIdx.x;           // 0..383, one column

    const size_t rowbase = (size_t)b * IMG + (size_t)(wy * SUB) * H;
    double s = 0.0;
#pragma unroll 4
    for (int r = 0; r < SUB; ++r) {
        size_t idx = rowbase + (size_t)r * H + c;
        float x  = preds[idx];
        float p  = 1.0f / (1.0f + __expf(-x));
        float pc = p < 1e-5f ? 1e-5f : p;
        float e  = -p * __logf(pc);
        ent[idx] = e;
        s += (double)e;
    }
    colsum[c] = s;
    __syncthreads();

    if (c < WS) {
        double t = 0.0;
        const double* base = colsum + c * SUB;
        for (int j = 0; j < SUB; ++j) t += base[j];
        float score = (float)(t / (double)WELEM);
        float d = score - 0.299f;
        int sel = d > 0.0f ? 1 : 0;
        int w = b * NW + wy * WS + c;
        flags[w]   = sel;
        maskOut[w] = sel ? 1.0f : 0.0f;
        if (fabsf(d) < 1e-4f) {
            int i = atomicAdd(count, 1);
            if (i < LISTCAP) list[i] = w;
        }
    }
}

// ---------------------------------------------------------------------------
// Kernel B (precise): recompute borderline windows exactly as the verified
// round-1 path did: f64 entropy -> round to f32 -> f64 sum -> f32 score.
__global__ void precise_kernel(const float* __restrict__ preds,
                               const int* __restrict__ count,
                               const int* __restrict__ list,
                               float* __restrict__ maskOut,
                               int* __restrict__ flags) {
    int n = *count;
    if (n > LISTCAP) n = LISTCAP;
    for (int i = blockIdx.x; i < n; i += gridDim.x) {
        int w  = list[i];
        int b  = w >> 8;
        int wi = w & 255;
        int wy = wi >> 4, wx = wi & 15;
        const float* basep = preds + (size_t)b * IMG + (size_t)(wy * SUB) * H + wx * SUB;
        double s = 0.0;
        for (int e = threadIdx.x; e < WELEM; e += 64) {
            int r = e / SUB, c = e % SUB;
            double x  = (double)basep[r * H + c];
            double p  = 1.0 / (1.0 + exp(-x));
            double pc = p < 1e-5 ? 1e-5 : p;
            float ef  = (float)(-p * log(pc));   // match stored-entropy rounding
            s += (double)ef;
        }
        for (int off = 32; off > 0; off >>= 1)
            s += __shfl_down(s, off, 64);
        if (threadIdx.x == 0) {
            float score = (float)(s / (double)WELEM);
            int sel = (score > 0.299f) ? 1 : 0;
            flags[w]   = sel;
            maskOut[w] = sel ? 1.0f : 0.0f;
        }
    }
}

// ---------------------------------------------------------------------------
// Kernel C: exclusive prefix over 16384 flags. 1024 threads, 16 flags each;
// wave shuffle scan + 16-wave LDS combine. Single block.
// NOTE: pos aliases the count/list region -- both are dead by the time this
// kernel runs (fused -> precise -> scan -> gather on one stream).
__global__ void scan_kernel(const int* __restrict__ flags,
                            int* __restrict__ pos) {
    int t    = threadIdx.x;
    int lane = t & 63, wave = t >> 6;
    int base = t * 16;
    int v[16];
    int s = 0;
#pragma unroll
    for (int j = 0; j < 16; ++j) { v[j] = flags[base + j]; s += v[j]; }

    int x = s;
#pragma unroll
    for (int off = 1; off < 64; off <<= 1) {
        int y = __shfl_up(x, off, 64);
        if (lane >= off) x += y;
    }
    __shared__ int wsum[16];
    __shared__ int woff[16];
    if (lane == 63) wsum[wave] = x;
    __syncthreads();
    if (t == 0) {
        int a = 0;
        for (int i = 0; i < 16; ++i) { woff[i] = a; a += wsum[i]; }
    }
    __syncthreads();

    int excl = woff[wave] + x - s;
#pragma unroll
    for (int j = 0; j < 16; ++j) { pos[base + j] = excl; excl += v[j]; }
}

// ---------------------------------------------------------------------------
// Kernel D: one block per window; selected windows copy h_inputs row and the
// image's input_features row to compacted slots, plus (y,x) coords.
__global__ void gather_kernel(const float* __restrict__ inF,
                              const float* __restrict__ hIn,
                              const int* __restrict__ flags,
                              const int* __restrict__ pos,
                              float* __restrict__ outL,
                              float* __restrict__ outH,
                              float* __restrict__ coords) {
    int w = blockIdx.x;
    if (!flags[w]) return;
    int k  = pos[w];
    int b  = w >> 8;
    int wi = w & 255;

    const float4* src_h = (const float4*)(hIn + (size_t)w * D);
    const float4* src_l = (const float4*)(inF + (size_t)b * D);
    float4* dst_h = (float4*)(outH + (size_t)k * D);
    float4* dst_l = (float4*)(outL + (size_t)k * D);

    for (int i = threadIdx.x; i < D / 4; i += blockDim.x) {
        dst_h[i] = src_h[i];
        dst_l[i] = src_l[i];
    }
    if (threadIdx.x == 0) {
        coords[2 * (size_t)k]     = (float)(wi >> 4);
        coords[2 * (size_t)k + 1] = (float)(wi & 15);
    }
}

// ---------------------------------------------------------------------------
extern "C" void kernel_launch(void* const* d_in, const int* in_sizes, int n_in,
                              void* d_out, int out_size, void* d_ws, size_t ws_size,
                              hipStream_t stream) {
    const float* input_features = (const float*)d_in[0];   // [B, D]
    const float* h_inputs       = (const float*)d_in[1];   // [B, NW, D]
    const float* preds          = (const float*)d_in[2];   // [B, 1, H, H]
    float* out = (float*)d_out;

    // out layout: l[K,D] | h[K,D] | mask[TOTW] | coords[K,2] | entropy[TOT]
    int K = (out_size - TOT - TOTW) / (2 * D + 2);
    float* outL      = out;
    float* outH      = out + (size_t)K * D;
    float* outMask   = out + (size_t)2 * K * D;
    float* outCoords = outMask + TOTW;
    float* outEnt    = outCoords + (size_t)2 * K;

    // ws layout (<= 128 KB, the size proven safe in round 1):
    //   flags[TOTW] | posArea[TOTW]
    // posArea doubles as {count, list[TOTW-1]} until scan_kernel overwrites
    // it with pos -- count/list are dead by then.
    int* flags   = (int*)d_ws;
    int* posArea = flags + TOTW;
    int* count   = posArea;
    int* list    = posArea + 1;
    int* pos     = posArea;

    hipMemsetAsync(count, 0, sizeof(int), stream);

    fused_kernel<<<B * WS, H, 0, stream>>>(preds, outEnt, outMask, flags, count, list);
    precise_kernel<<<128, 64, 0, stream>>>(preds, count, list, outMask, flags);
    scan_kernel<<<1, 1024, 0, stream>>>(flags, pos);
    gather_kernel<<<TOTW, 256, 0, stream>>>(input_features, h_inputs, flags, pos,
                                            outL, outH, outCoords);
}